// Round 16
// baseline (11702.684 us; speedup 1.0000x reference)
//
#include <hip/hip_runtime.h>
#include <cstdint>

typedef float f32x4 __attribute__((ext_vector_type(4)));

// Problem constants
static constexpr int Hdim = 1024;
static constexpr int Vdim = 128;
static constexpr int Bdim = 64;
static constexpr int Sdim = 512;

// Persistent kernel geometry (low-fan-in corner of the volume/jitter model)
static constexpr int NB   = 8;     // batches per block (= per cluster)
static constexpr int NI   = 64;    // output columns per block
static constexpr int KCH  = 32;    // k elements per thread chunk
static constexpr int SL   = 1028;  // LDS h row stride in floats
static constexpr int NBLK = 128;   // total blocks (1 per CU, half the GPU)
static constexpr int BPC  = 16;    // blocks per cluster (fan-in halved again)
static constexpr int NCL  = 8;     // clusters (NCL*NB = 64 batches)

// ---------------- prep: pack U^T ----------------
// Up[s][k][il] = U[s*64+il][k]  (block s streams a contiguous [1024][64] slice)
__global__ void __launch_bounds__(256) pack_u_kernel(const float* __restrict__ U,
                                                     float* __restrict__ Up) {
  __shared__ float tile[32][257];
  const int sh   = blockIdx.x;      // 0..31: (slice, half)
  const int s    = sh >> 1, half = sh & 1;
  const int k0   = blockIdx.y * 256;  // 0,256,512,768
  const int t    = threadIdx.x;
  #pragma unroll
  for (int r = 0; r < 32; ++r)
    tile[r][t] = U[(size_t)(s * 64 + half * 32 + r) * Hdim + k0 + t];
  __syncthreads();
  #pragma unroll
  for (int r2 = 0; r2 < 32; ++r2) {
    int g  = r2 * 256 + t;          // g = kr*32 + il
    int il = g & 31, kr = g >> 5;   // kr 0..255
    Up[((size_t)s * Hdim + k0 + kr) * 64 + half * 32 + il] = tile[il][kr];
  }
}

// ---------------- prep: W [1024][128] -> Wt [128][1024] ----------------
__global__ void transpose_w_kernel(const float* __restrict__ in, float* __restrict__ out) {
  __shared__ float tile[32][33];
  const int bx = blockIdx.x * 32;   // col base (vocab)
  const int by = blockIdx.y * 32;   // row base (hidden)
  const int tx = threadIdx.x, ty = threadIdx.y;  // 32 x 8
  #pragma unroll
  for (int dy = 0; dy < 32; dy += 8)
    tile[ty + dy][tx] = in[(size_t)(by + ty + dy) * Vdim + bx + tx];
  __syncthreads();
  #pragma unroll
  for (int dy = 0; dy < 32; dy += 8)
    out[(size_t)(bx + ty + dy) * Hdim + by + tx] = tile[tx][ty + dy];
}

// ---------------- persistent recurrence + fused logits ----------------
// Same proven R11 sync protocol (IF-coherent sc0sc1 h exchange, per-cluster
// step-tag flags, vmcnt drain before publish). Geometry: 128 blocks, cluster
// of 16, NI=64 columns/block -> staging volume 4 MB/step, fan-in 16.
// U locality: XCD = blk%8, s = blk&15 -> 2 distinct slices/XCD (512 KB, L2).
// Co-residency (plain-launch fallback): ~42 KB LDS -> 3 blocks/CU capacity;
// grid 128 = 1 block/CU on half the CUs.
__global__ void __launch_bounds__(256, 1) rnn_persist_kernel(
    const float* __restrict__ Up,   // [16][1024][64] packed U^T
    const float* __restrict__ Wt,   // [V][H]
    const int*   __restrict__ X,    // [B][S]
    const float* __restrict__ lw,   // [V][H]
    const float* __restrict__ lb,   // [V]
    float* __restrict__ h0,
    float* __restrict__ h1,
    unsigned int* __restrict__ flags, // [NCL][BPC] step-tags
    float* __restrict__ out)        // [B][S][V] (logits; softmaxed later)
{
  __shared__ float hsm[NB * SL];          // staged h_t slice (8 rows, 33 KB)
  __shared__ float part[4][NB][NI];       // per-wave recurrence partials (8 KB)
  __shared__ float partv[4][NB][8];       // per-wave logit partials (1 KB)

  const int tid  = threadIdx.x;
  const int blk  = blockIdx.x;
  const int cl   = blk >> 4;              // cluster 0..7
  const int s    = blk & 15;              // column-slice 0..15
  const int i0   = s * NI;                // global column base
  const int bg0  = cl * NB;               // global batch base
  const int kp   = tid >> 3;              // 0..31
  const int b    = tid & 7;               // 0..7
  const int w    = tid >> 6;              // wave 0..3
  const int lane = tid & 63;
  const float* Ublk = Up + (size_t)s * Hdim * NI;

  auto stage_h = [&](int t) {
    if (t == 0) {
      const f32x4 z = (f32x4){0.f, 0.f, 0.f, 0.f};
      #pragma unroll
      for (int r = 0; r < NB; ++r)
        *((f32x4*)&hsm[r * SL + tid * 4]) = z;
    } else {
      const float* hc = (t & 1) ? h1 : h0;
      const float* p = hc + (size_t)bg0 * Hdim + tid * 4;
      f32x4 v0, v1, v2, v3, v4, v5, v6, v7;
      // Coalesced 16B system-scope loads (IF-coherent, L1/L2 bypass).
      asm volatile(
          "global_load_dwordx4 %0, %8, off sc0 sc1\n\t"
          "global_load_dwordx4 %1, %9, off sc0 sc1\n\t"
          "global_load_dwordx4 %2, %10, off sc0 sc1\n\t"
          "global_load_dwordx4 %3, %11, off sc0 sc1\n\t"
          "global_load_dwordx4 %4, %12, off sc0 sc1\n\t"
          "global_load_dwordx4 %5, %13, off sc0 sc1\n\t"
          "global_load_dwordx4 %6, %14, off sc0 sc1\n\t"
          "global_load_dwordx4 %7, %15, off sc0 sc1\n\t"
          "s_waitcnt vmcnt(0)"
          : "=&v"(v0), "=&v"(v1), "=&v"(v2), "=&v"(v3),
            "=&v"(v4), "=&v"(v5), "=&v"(v6), "=&v"(v7)
          : "v"(p), "v"(p + Hdim), "v"(p + 2 * Hdim), "v"(p + 3 * Hdim),
            "v"(p + 4 * Hdim), "v"(p + 5 * Hdim), "v"(p + 6 * Hdim), "v"(p + 7 * Hdim)
          : "memory");
      *((f32x4*)&hsm[0 * SL + tid * 4]) = v0;
      *((f32x4*)&hsm[1 * SL + tid * 4]) = v1;
      *((f32x4*)&hsm[2 * SL + tid * 4]) = v2;
      *((f32x4*)&hsm[3 * SL + tid * 4]) = v3;
      *((f32x4*)&hsm[4 * SL + tid * 4]) = v4;
      *((f32x4*)&hsm[5 * SL + tid * 4]) = v5;
      *((f32x4*)&hsm[6 * SL + tid * 4]) = v6;
      *((f32x4*)&hsm[7 * SL + tid * 4]) = v7;
    }
  };

  auto logits_partial = [&]() {  // h_t in hsm -> partv (8 vocab rows 8s..8s+7)
    float a[8];
    #pragma unroll
    for (int r = 0; r < 8; ++r) a[r] = 0.f;
    const f32x4* hr4 = (const f32x4*)&hsm[b * SL + kp * KCH];
    #pragma unroll
    for (int r = 0; r < 8; ++r) {
      const f32x4* lwr = (const f32x4*)(lw + (size_t)(8 * s + r) * Hdim + kp * KCH);
      float ar = 0.f;
      #pragma unroll
      for (int j = 0; j < KCH / 4; ++j) {
        int jj = (j + kp) & (KCH / 4 - 1);
        f32x4 hv = hr4[jj];
        f32x4 qv = lwr[jj];
        #pragma unroll
        for (int e = 0; e < 4; ++e) ar += hv[e] * qv[e];
      }
      a[r] = ar;
    }
    #pragma unroll
    for (int r = 0; r < 8; ++r) {
      a[r] += __shfl_xor(a[r], 8, 64);
      a[r] += __shfl_xor(a[r], 16, 64);
      a[r] += __shfl_xor(a[r], 32, 64);
    }
    if ((lane & 56) == 0) {
      *((f32x4*)&partv[w][b][0]) = (f32x4){a[0], a[1], a[2], a[3]};
      *((f32x4*)&partv[w][b][4]) = (f32x4){a[4], a[5], a[6], a[7]};
    }
  };

  auto logits_combine = [&](int tt) {  // partv -> out[:, tt, 8s..8s+7]
    if (tid >= 128 && tid < 192) {
      const int q = tid - 128;
      const int bb = q >> 3, vv = q & 7;
      float lv = partv[0][bb][vv] + partv[1][bb][vv] + partv[2][bb][vv] + partv[3][bb][vv];
      lv += lb[8 * s + vv];
      out[((size_t)(bg0 + bb) * Sdim + tt) * Vdim + 8 * s + vv] = lv;
    }
  };

  for (int t = 0; t < Sdim; ++t) {
    stage_h(t);
    __syncthreads();

    // ---- recurrence: acc[i] = sum over this thread's k-chunk of U^T[k][i]*h[k] ----
    {
      float acc[NI];
      #pragma unroll
      for (int i = 0; i < NI; ++i) acc[i] = 0.f;
      const float* hr = &hsm[b * SL + kp * KCH];
      const f32x4* ub = (const f32x4*)(Ublk + (size_t)kp * KCH * NI);
      #pragma unroll 2
      for (int j = 0; j < KCH; ++j) {
        int jj = (j + kp) & (KCH - 1);
        float hv = hr[jj];
        const f32x4* u = ub + (size_t)jj * (NI / 4);
        #pragma unroll
        for (int q = 0; q < NI / 4; ++q) {
          const f32x4 uq = u[q];
          acc[q * 4 + 0] += uq[0] * hv;
          acc[q * 4 + 1] += uq[1] * hv;
          acc[q * 4 + 2] += uq[2] * hv;
          acc[q * 4 + 3] += uq[3] * hv;
        }
      }
      #pragma unroll
      for (int i = 0; i < NI; ++i) {
        acc[i] += __shfl_xor(acc[i], 8, 64);
        acc[i] += __shfl_xor(acc[i], 16, 64);
        acc[i] += __shfl_xor(acc[i], 32, 64);
      }
      if ((lane & 56) == 0) {
        #pragma unroll
        for (int i = 0; i < NI; i += 4)
          *((f32x4*)&part[w][b][i]) = (f32x4){acc[i], acc[i + 1], acc[i + 2], acc[i + 3]};
      }
    }
    __syncthreads();

    // ---- h_{t+1} update + IF store (256 threads x 2 values = NB*NI = 512) ----
    {
      const int b2 = tid >> 5, i2 = tid & 31;
      float v1 = part[0][b2][i2] + part[1][b2][i2] + part[2][b2][i2] + part[3][b2][i2];
      float v2 = part[0][b2][i2 + 32] + part[1][b2][i2 + 32] +
                 part[2][b2][i2 + 32] + part[3][b2][i2 + 32];
      const int x = X[(bg0 + b2) * Sdim + t];
      v1 += Wt[(size_t)x * Hdim + i0 + i2];
      v2 += Wt[(size_t)x * Hdim + i0 + 32 + i2];
      v1 = tanhf(v1);
      v2 = tanhf(v2);
      float* hn = (t & 1) ? h0 : h1;
      __hip_atomic_store(&hn[(size_t)(bg0 + b2) * Hdim + i0 + i2], v1,
                         __ATOMIC_RELAXED, __HIP_MEMORY_SCOPE_SYSTEM);
      __hip_atomic_store(&hn[(size_t)(bg0 + b2) * Hdim + i0 + 32 + i2], v2,
                         __ATOMIC_RELAXED, __HIP_MEMORY_SCOPE_SYSTEM);
    }

    // ---- signal: drain own h-stores to IF, then publish step-tag ----
    asm volatile("s_waitcnt vmcnt(0)" ::: "memory");
    __syncthreads();                       // all waves' h-stores IF-complete
    if (tid == 0)
      __hip_atomic_store(&flags[cl * BPC + s], (unsigned)(t + 1),
                         __ATOMIC_RELAXED, __HIP_MEMORY_SCOPE_SYSTEM);

    // ---- barrier shadow: logits for step t-1 from hsm (h_t) ----
    if (t > 0) logits_partial();
    __syncthreads();
    if (t > 0) logits_combine(t - 1);

    // ---- wave-parallel poll: lane l watches flag[cl][l & 15] ----
    if (tid < 64) {
      const unsigned int tag = (unsigned)(t + 1);
      unsigned int* f = &flags[cl * BPC + (tid & (BPC - 1))];
      while (true) {
        unsigned int fv = __hip_atomic_load(f, __ATOMIC_RELAXED, __HIP_MEMORY_SCOPE_SYSTEM);
        if (__all((int)(fv >= tag))) break;
        __builtin_amdgcn_s_sleep(1);
      }
    }
    __syncthreads();
  }

  // ---- epilogue: logits for the final state h_S ----
  stage_h(Sdim);
  __syncthreads();
  logits_partial();
  __syncthreads();
  logits_combine(Sdim - 1);
}

// ---------------- in-place softmax over last dim (128) ----------------
__global__ void __launch_bounds__(256) softmax_kernel(float* __restrict__ out) {
  const int row = blockIdx.x * 4 + (threadIdx.x >> 6);  // one wave per row
  const int l = threadIdx.x & 63;
  float* rp = out + (size_t)row * Vdim;
  float2 v = *((const float2*)&rp[l * 2]);
  float m = fmaxf(v.x, v.y);
  #pragma unroll
  for (int d = 1; d < 64; d <<= 1) m = fmaxf(m, __shfl_xor(m, d, 64));
  float e0 = expf(v.x - m), e1 = expf(v.y - m);
  float ss = e0 + e1;
  #pragma unroll
  for (int d = 1; d < 64; d <<= 1) ss += __shfl_xor(ss, d, 64);
  const float inv = 1.f / ss;
  *((float2*)&rp[l * 2]) = make_float2(e0 * inv, e1 * inv);
}

extern "C" void kernel_launch(void* const* d_in, const int* in_sizes, int n_in,
                              void* d_out, int out_size, void* d_ws, size_t ws_size,
                              hipStream_t stream) {
  const int*   X  = (const int*)d_in[0];
  const float* U  = (const float*)d_in[1];
  const float* W  = (const float*)d_in[2];
  const float* lw = (const float*)d_in[3];
  const float* lb = (const float*)d_in[4];
  float* out = (float*)d_out;

  // workspace layout (floats): Up[1M] | Wt[128K] | h0[64K] | h1[64K] | flags
  float* Up = (float*)d_ws;
  float* Wt = Up + (size_t)1024 * 1024;
  float* h0 = Wt + (size_t)128 * 1024;
  float* h1 = h0 + (size_t)64 * 1024;
  unsigned int* flags = (unsigned int*)(h1 + (size_t)64 * 1024);
  const size_t need = ((size_t)1024 * 1024 + 128 * 1024 + 2 * 64 * 1024) * 4 + NCL * BPC * 4;
  if (ws_size < need) return;

  // flags must be zero each call (tags are per-launch monotonic; the graph
  // replays this memset, so re-validation after timing stays correct).
  hipMemsetAsync(flags, 0, (size_t)NCL * BPC * sizeof(unsigned int), stream);

  hipLaunchKernelGGL(pack_u_kernel, dim3(32, 4), dim3(256), 0, stream, U, Up);
  hipLaunchKernelGGL(transpose_w_kernel, dim3(4, 32), dim3(32, 8), 0, stream, W, Wt);

  void* args[] = {(void*)&Up, (void*)&Wt, (void*)&X, (void*)&lw, (void*)&lb,
                  (void*)&h0, (void*)&h1, (void*)&flags, (void*)&out};
  hipError_t ce = hipLaunchCooperativeKernel((void*)rnn_persist_kernel,
                                             dim3(NBLK), dim3(256), args, 0, stream);
  if (ce != hipSuccess) {
    // Silent-coop-failure fallback: plain launch. All 128 blocks co-resident
    // by resource arithmetic (1 block/CU on half the CUs), so the flag
    // barrier is safe without the cooperative API.
    hipLaunchKernelGGL(rnn_persist_kernel, dim3(NBLK), dim3(256), 0, stream,
                       Up, Wt, X, lw, lb, h0, h1, flags, out);
  }

  hipLaunchKernelGGL(softmax_kernel, dim3((Bdim * Sdim) / 4), dim3(256), 0, stream, out);
}

// Round 17
// 6180.990 us; speedup vs baseline: 1.8933x; 1.8933x over previous
//
#include <hip/hip_runtime.h>
#include <cstdint>

// Problem constants
static constexpr int Hdim = 1024;
static constexpr int Vdim = 128;
static constexpr int Bdim = 64;
static constexpr int Sdim = 512;

// Persistent kernel geometry
static constexpr int NB   = 8;     // batches per block (= per cluster)
static constexpr int NI   = 16;    // output rows (i) per block
static constexpr int KCH  = 32;    // k elements per thread chunk
static constexpr int SL   = 1028;  // LDS h row stride in floats
static constexpr int NBLK = 512;   // total blocks
static constexpr int BPC  = 64;    // blocks per cluster
static constexpr int NCL  = 8;     // clusters (NCL*NB = 64 batches)

// ---------------- prep: pack U^T ----------------
// Up[s][k][il] = U[s*16+il][k]   (block s streams a contiguous [1024][16] slice)
__global__ void __launch_bounds__(256) pack_u_kernel(const float* __restrict__ U,
                                                     float* __restrict__ Up) {
  __shared__ float tile[16][257];
  const int s  = blockIdx.x;        // 0..63 (i-group)
  const int k0 = blockIdx.y * 256;  // 0,256,512,768
  const int t  = threadIdx.x;
  #pragma unroll
  for (int r = 0; r < 16; ++r)
    tile[r][t] = U[(size_t)(s * 16 + r) * Hdim + k0 + t];
  __syncthreads();
  const size_t base = ((size_t)s * Hdim + k0) * 16;
  #pragma unroll
  for (int r2 = 0; r2 < 16; ++r2) {
    int g = r2 * 256 + t;           // g = k_rel*16 + il
    Up[base + g] = tile[g & 15][g >> 4];
  }
}

// ---------------- prep: W [1024][128] -> Wt [128][1024] ----------------
__global__ void transpose_w_kernel(const float* __restrict__ in, float* __restrict__ out) {
  __shared__ float tile[32][33];
  const int bx = blockIdx.x * 32;   // col base (vocab)
  const int by = blockIdx.y * 32;   // row base (hidden)
  const int tx = threadIdx.x, ty = threadIdx.y;  // 32 x 8
  #pragma unroll
  for (int dy = 0; dy < 32; dy += 8)
    tile[ty + dy][tx] = in[(size_t)(by + ty + dy) * Vdim + bx + tx];
  __syncthreads();
  #pragma unroll
  for (int dy = 0; dy < 32; dy += 8)
    out[(size_t)(bx + ty + dy) * Hdim + by + tx] = tile[tx][ty + dy];
}

// ---------------- persistent recurrence + fused logits ----------------
// Co-residency arithmetic (for plain-launch fallback): LDS 35328 B -> 4
// blocks/CU capacity; VGPR 80 -> >=4; threads -> 8. Grid 512 = 2/CU on 256
// CUs <= capacity, so ALL blocks are resident and the flag barrier
// progresses regardless of dispatch order.
__global__ void __launch_bounds__(256, 2) rnn_persist_kernel(
    const float* __restrict__ Up,   // [64][1024][16] packed U^T
    const float* __restrict__ Wt,   // [V][H]
    const int*   __restrict__ X,    // [B][S]
    const float* __restrict__ lw,   // [V][H]
    const float* __restrict__ lb,   // [V]
    float* __restrict__ h0,
    float* __restrict__ h1,
    unsigned int* __restrict__ flags, // [NCL][BPC] step-tags
    float* __restrict__ out)        // [B][S][V] (logits; softmaxed later)
{
  __shared__ float hsm[NB * SL];          // staged h_t slice (8 rows)
  __shared__ float part[4][NB][NI];       // per-wave recurrence partials
  __shared__ float partv[4][NB][2];       // per-wave logit partials

  const int tid  = threadIdx.x;
  const int blk  = blockIdx.x;
  const int cl   = blk >> 6;              // cluster 0..7
  const int s    = blk & 63;              // block-in-cluster 0..63
  const int i0   = s * NI;                // global i base
  const int bg0  = cl * NB;               // global batch base
  const int kp   = tid >> 3;              // 0..31
  const int b    = tid & 7;               // 0..7
  const int w    = tid >> 6;              // wave 0..3
  const int lane = tid & 63;
  const float* Ublk = Up + (size_t)s * Hdim * NI;

  auto stage_h = [&](int t) {
    if (t == 0) {
      #pragma unroll
      for (int r = 0; r < NB; ++r) {
        float* dst = &hsm[r * SL + tid * 4];
        dst[0] = 0.f; dst[1] = 0.f; dst[2] = 0.f; dst[3] = 0.f;
      }
    } else {
      const float* hc = (t & 1) ? h1 : h0;
      // 8B system-scope loads: coherent at IF, bypass L1/L2, no cache flushes.
      const unsigned long long* src8 =
          (const unsigned long long*)(hc + (size_t)bg0 * Hdim);
      #pragma unroll
      for (int r = 0; r < NB; ++r) {
        unsigned long long u0 = __hip_atomic_load(&src8[r * (Hdim / 2) + tid * 2],
                                                  __ATOMIC_RELAXED, __HIP_MEMORY_SCOPE_SYSTEM);
        unsigned long long u1 = __hip_atomic_load(&src8[r * (Hdim / 2) + tid * 2 + 1],
                                                  __ATOMIC_RELAXED, __HIP_MEMORY_SCOPE_SYSTEM);
        unsigned long long* dst = (unsigned long long*)&hsm[r * SL + tid * 4];
        dst[0] = u0; dst[1] = u1;
      }
    }
  };

  auto logits_partial = [&]() {  // h_t in hsm -> partv (per-wave)
    float a0 = 0.f, a1 = 0.f;
    const float4* lw0 = (const float4*)(lw + (size_t)(2 * s)     * Hdim + kp * KCH);
    const float4* lw1 = (const float4*)(lw + (size_t)(2 * s + 1) * Hdim + kp * KCH);
    const float* hr = &hsm[b * SL + kp * KCH];
    #pragma unroll
    for (int j = 0; j < KCH / 4; ++j) {
      int jj = (j + kp) & (KCH / 4 - 1);
      float4 hv = *((const float4*)&hr[4 * jj]);
      float4 w0 = lw0[jj];
      float4 w1 = lw1[jj];
      a0 += hv.x * w0.x + hv.y * w0.y + hv.z * w0.z + hv.w * w0.w;
      a1 += hv.x * w1.x + hv.y * w1.y + hv.z * w1.z + hv.w * w1.w;
    }
    a0 += __shfl_xor(a0, 8, 64);  a1 += __shfl_xor(a1, 8, 64);
    a0 += __shfl_xor(a0, 16, 64); a1 += __shfl_xor(a1, 16, 64);
    a0 += __shfl_xor(a0, 32, 64); a1 += __shfl_xor(a1, 32, 64);
    if ((lane & 56) == 0) { partv[w][b][0] = a0; partv[w][b][1] = a1; }
  };

  auto logits_combine = [&](int tt) {  // partv -> out[:, tt, 2s..2s+1]
    if (tid >= 128 && tid < 128 + 2 * NB) {
      const int q = tid - 128;
      const int bb = q >> 1, vv = q & 1;
      float lv = partv[0][bb][vv] + partv[1][bb][vv] + partv[2][bb][vv] + partv[3][bb][vv];
      lv += lb[2 * s + vv];
      out[((size_t)(bg0 + bb) * Sdim + tt) * Vdim + 2 * s + vv] = lv;
    }
  };

  for (int t = 0; t < Sdim; ++t) {
    stage_h(t);
    __syncthreads();

    // ---- recurrence: acc[i] = sum over this thread's k-chunk of U^T[k][i]*h[k] ----
    {
      float acc[NI];
      #pragma unroll
      for (int i = 0; i < NI; ++i) acc[i] = 0.f;
      const float* hr = &hsm[b * SL + kp * KCH];
      const float4* ub = (const float4*)(Ublk + (size_t)kp * KCH * NI);
      #pragma unroll 4
      for (int j = 0; j < KCH; ++j) {
        int jj = (j + kp) & (KCH - 1);
        float hv = hr[jj];
        const float4* u = ub + (size_t)jj * 4;
        float4 u0 = u[0], u1 = u[1], u2 = u[2], u3 = u[3];
        acc[0]  += u0.x * hv; acc[1]  += u0.y * hv; acc[2]  += u0.z * hv; acc[3]  += u0.w * hv;
        acc[4]  += u1.x * hv; acc[5]  += u1.y * hv; acc[6]  += u1.z * hv; acc[7]  += u1.w * hv;
        acc[8]  += u2.x * hv; acc[9]  += u2.y * hv; acc[10] += u2.z * hv; acc[11] += u2.w * hv;
        acc[12] += u3.x * hv; acc[13] += u3.y * hv; acc[14] += u3.z * hv; acc[15] += u3.w * hv;
      }
      #pragma unroll
      for (int i = 0; i < NI; ++i) {
        acc[i] += __shfl_xor(acc[i], 8, 64);
        acc[i] += __shfl_xor(acc[i], 16, 64);
        acc[i] += __shfl_xor(acc[i], 32, 64);
      }
      if ((lane & 56) == 0) {
        #pragma unroll
        for (int i = 0; i < NI; i += 4)
          *((float4*)&part[w][b][i]) = make_float4(acc[i], acc[i + 1], acc[i + 2], acc[i + 3]);
      }
    }
    __syncthreads();

    // ---- h_{t+1} update + IF store ----
    if (tid < NB * NI) {
      const int b2 = tid >> 4, i2 = tid & 15;
      float v = part[0][b2][i2] + part[1][b2][i2] + part[2][b2][i2] + part[3][b2][i2];
      const int x = X[(bg0 + b2) * Sdim + t];
      v += Wt[(size_t)x * Hdim + i0 + i2];
      v = tanhf(v);
      float* hn = (t & 1) ? h0 : h1;
      __hip_atomic_store(&hn[(size_t)(bg0 + b2) * Hdim + i0 + i2], v,
                         __ATOMIC_RELAXED, __HIP_MEMORY_SCOPE_SYSTEM);
    }

    // ---- signal: drain own h-stores to IF, then publish step-tag ----
    asm volatile("s_waitcnt vmcnt(0)" ::: "memory");
    __syncthreads();                       // all waves' h-stores IF-complete
    if (tid == 0)
      __hip_atomic_store(&flags[cl * BPC + s], (unsigned)(t + 1),
                         __ATOMIC_RELAXED, __HIP_MEMORY_SCOPE_SYSTEM);

    // ---- barrier shadow: logits for step t-1 from hsm (h_t) ----
    if (t > 0) logits_partial();
    __syncthreads();
    if (t > 0) logits_combine(t - 1);

    // ---- wave-parallel poll: lane l watches flag[cl][l] ----
    if (tid < 64) {
      const unsigned int tag = (unsigned)(t + 1);
      unsigned int* f = &flags[cl * BPC + tid];
      while (true) {
        unsigned int fv = __hip_atomic_load(f, __ATOMIC_RELAXED, __HIP_MEMORY_SCOPE_SYSTEM);
        if (__all((int)(fv >= tag))) break;
        __builtin_amdgcn_s_sleep(1);
      }
    }
    __syncthreads();
  }

  // ---- epilogue: logits for the final state h_S ----
  stage_h(Sdim);
  __syncthreads();
  logits_partial();
  __syncthreads();
  logits_combine(Sdim - 1);
}

// ---------------- in-place softmax over last dim (128) ----------------
__global__ void __launch_bounds__(256) softmax_kernel(float* __restrict__ out) {
  const int row = blockIdx.x * 4 + (threadIdx.x >> 6);  // one wave per row
  const int l = threadIdx.x & 63;
  float* rp = out + (size_t)row * Vdim;
  float2 v = *((const float2*)&rp[l * 2]);
  float m = fmaxf(v.x, v.y);
  #pragma unroll
  for (int d = 1; d < 64; d <<= 1) m = fmaxf(m, __shfl_xor(m, d, 64));
  float e0 = expf(v.x - m), e1 = expf(v.y - m);
  float ss = e0 + e1;
  #pragma unroll
  for (int d = 1; d < 64; d <<= 1) ss += __shfl_xor(ss, d, 64);
  const float inv = 1.f / ss;
  *((float2*)&rp[l * 2]) = make_float2(e0 * inv, e1 * inv);
}

extern "C" void kernel_launch(void* const* d_in, const int* in_sizes, int n_in,
                              void* d_out, int out_size, void* d_ws, size_t ws_size,
                              hipStream_t stream) {
  const int*   X  = (const int*)d_in[0];
  const float* U  = (const float*)d_in[1];
  const float* W  = (const float*)d_in[2];
  const float* lw = (const float*)d_in[3];
  const float* lb = (const float*)d_in[4];
  float* out = (float*)d_out;

  // workspace layout (floats): Up[1M] | Wt[128K] | h0[64K] | h1[64K] | flags
  float* Up = (float*)d_ws;
  float* Wt = Up + (size_t)1024 * 1024;
  float* h0 = Wt + (size_t)128 * 1024;
  float* h1 = h0 + (size_t)64 * 1024;
  unsigned int* flags = (unsigned int*)(h1 + (size_t)64 * 1024);
  const size_t need = ((size_t)1024 * 1024 + 128 * 1024 + 2 * 64 * 1024) * 4 + NCL * Sdim * 4;
  if (ws_size < need) return;

  // flags must be zero each call (tags are per-launch monotonic; the graph
  // replays this memset, so re-validation after timing stays correct).
  hipMemsetAsync(flags, 0, (size_t)NCL * Sdim * sizeof(unsigned int), stream);

  hipLaunchKernelGGL(pack_u_kernel, dim3(64, 4), dim3(256), 0, stream, U, Up);
  hipLaunchKernelGGL(transpose_w_kernel, dim3(4, 32), dim3(32, 8), 0, stream, W, Wt);

  void* args[] = {(void*)&Up, (void*)&Wt, (void*)&X, (void*)&lw, (void*)&lb,
                  (void*)&h0, (void*)&h1, (void*)&flags, (void*)&out};
  hipError_t ce = hipLaunchCooperativeKernel((void*)rnn_persist_kernel,
                                             dim3(NBLK), dim3(256), args, 0, stream);
  if (ce != hipSuccess) {
    // Silent-coop-failure fallback: plain launch. All 512 blocks are
    // co-resident by resource arithmetic (see kernel comment), so the
    // flag barrier is safe without the cooperative API.
    hipLaunchKernelGGL(rnn_persist_kernel, dim3(NBLK), dim3(256), 0, stream,
                       Up, Wt, X, lw, lb, h0, h1, flags, out);
  }

  hipLaunchKernelGGL(softmax_kernel, dim3((Bdim * Sdim) / 4), dim3(256), 0, stream, out);
}